// Round 1
// 1733.198 us; speedup vs baseline: 1.2206x; 1.2206x over previous
//
#include <hip/hip_runtime.h>
#include <math.h>

#define NN 50000
#define NE 800000
#define DNODE 128
#define DEDGE 64
#define HD 96

__device__ __forceinline__ float lrelu(float x){ return x > 0.f ? x : 0.2f*x; }

// ---- CSR build ----------------------------------------------------------
__global__ void k_count(const int* __restrict__ dst, int* __restrict__ cnt){
  int e = blockIdx.x*256 + threadIdx.x;
  if (e < NE) atomicAdd(&cnt[dst[e]], 1);
}

// shfl-based single-block scan: 3 barriers per 1024-chunk
__global__ __launch_bounds__(1024) void k_scan(const int* __restrict__ cnt,
                                               int* __restrict__ rowptr){
  __shared__ int wsum[16];
  __shared__ int carry_s;
  const int t = threadIdx.x;
  const int lane = t & 63, w = t >> 6;
  if (t == 0) carry_s = 0;
  __syncthreads();
  const int nch = (NN + 1023)/1024;
  for (int c=0;c<nch;c++){
    int i = c*1024 + t;
    int v = (i < NN) ? cnt[i] : 0;
    int s = v;
    #pragma unroll
    for (int o=1;o<64;o<<=1){
      int u = __shfl_up(s, o, 64);
      if (lane >= o) s += u;
    }
    if (lane == 63) wsum[w] = s;
    __syncthreads();
    if (t < 16){
      int x = wsum[t];
      #pragma unroll
      for (int o=1;o<16;o<<=1){
        int u = __shfl_up(x, o, 64);
        if (t >= o) x += u;
      }
      wsum[t] = x;
    }
    __syncthreads();
    int total = wsum[15];
    int base = carry_s + (w ? wsum[w-1] : 0);
    if (i < NN) rowptr[i] = base + s - v;     // exclusive prefix
    __syncthreads();
    if (t == 0) carry_s += total;
  }
  __syncthreads();
  if (t == 0) rowptr[NN] = carry_s;
}

__global__ void k_fill(const int* __restrict__ src, const int* __restrict__ dst,
                       const int* __restrict__ rowptr, int* __restrict__ fillc,
                       int* __restrict__ perm, int* __restrict__ src_s){
  int e = blockIdx.x*256 + threadIdx.x;
  if (e >= NE) return;
  int d = dst[e];
  int pos = rowptr[d] + atomicAdd(&fillc[d], 1);
  perm[pos]  = e;
  src_s[pos] = src[e];
}

// ---- small helpers ------------------------------------------------------
// v[k] = sum_j We[k,j] * ae[j]
__global__ void k_vec(const float* __restrict__ We, const float* __restrict__ ae,
                      float* __restrict__ v, int K){
  int k = threadIdx.x;
  if (k < K){
    float s = 0.f;
    for (int j=0;j<HD;j++) s += We[k*HD + j]*ae[j];
    v[k] = s;
  }
}

// elr[e] = dot(Ein[e,:], v)   (only needed as a standalone pass for layer 0)
__global__ void k_elr(const float* __restrict__ Ein, const float* __restrict__ v,
                      float* __restrict__ elr, int K){
  int e = blockIdx.x*256 + threadIdx.x;
  if (e >= NE) return;
  const float4* row = (const float4*)(Ein + (size_t)e*K);
  float s = 0.f;
  for (int k=0;k<K/4;k++){
    float4 a = row[k];
    float4 b = ((const float4*)v)[k];
    s += a.x*b.x + a.y*b.y + a.z*b.z + a.w*b.w;
  }
  elr[e] = s;
}

// ---- GEMMs: 4 rows x 12 cols per thread (LDS reads amortized 4x) --------
// Y[M,96] = X[M,K] @ W[K,96]; optional fused hs=Y@va, hd=Y@vb epilogue.
template<int K, bool DOTS>
__global__ __launch_bounds__(256,4) void k_nodegemm_t(const float* __restrict__ X,
    const float* __restrict__ W, float* __restrict__ Y, int M,
    const float* __restrict__ va, const float* __restrict__ vb,
    float* __restrict__ hs, float* __restrict__ hd){
  __shared__ float Wl[K*HD];
  for (int idx=threadIdx.x; idx<K*HD/4; idx+=256)
    ((float4*)Wl)[idx] = ((const float4*)W)[idx];
  __syncthreads();
  const int r  = threadIdx.x >> 3;          // 0..31
  const int c0 = (threadIdx.x & 7)*12;      // 0..84
  const int r0 = blockIdx.x*128 + r;        // rows r0 + 32*q
  float acc[4][12];
  #pragma unroll
  for (int q=0;q<4;q++)
    #pragma unroll
    for (int j=0;j<12;j++) acc[q][j]=0.f;
  for (int k=0;k<K;k+=4){
    float4 xv[4];
    #pragma unroll
    for (int q=0;q<4;q++){
      int row = r0 + 32*q;
      xv[q] = (row < M) ? *(const float4*)(X + (size_t)row*K + k)
                        : make_float4(0.f,0.f,0.f,0.f);
    }
    #pragma unroll
    for (int kk=0;kk<4;kk++){
      float wv[12];
      const float* wr = Wl + (k+kk)*HD + c0;
      #pragma unroll
      for (int j=0;j<12;j++) wv[j] = wr[j];
      #pragma unroll
      for (int q=0;q<4;q++){
        float xs = ((const float*)&xv[q])[kk];
        #pragma unroll
        for (int j=0;j<12;j++) acc[q][j] += xs*wv[j];
      }
    }
  }
  float vva[12], vvb[12];
  if constexpr (DOTS){
    #pragma unroll
    for (int j=0;j<12;j++){ vva[j]=va[c0+j]; vvb[j]=vb[c0+j]; }
  }
  #pragma unroll
  for (int q=0;q<4;q++){
    int row = r0 + 32*q;
    if (row >= M) continue;
    float* yr = Y + (size_t)row*HD + c0;
    float d1=0.f, d2=0.f;
    #pragma unroll
    for (int j=0;j<12;j++){
      float o = acc[q][j];
      yr[j] = o;
      if constexpr (DOTS){ d1 += o*vva[j]; d2 += o*vvb[j]; }
    }
    if constexpr (DOTS){
      #pragma unroll
      for (int o=1;o<8;o<<=1){ d1 += __shfl_xor(d1,o,64); d2 += __shfl_xor(d2,o,64); }
      if ((threadIdx.x&7)==0){ hs[row]=d1; hd[row]=d2; }
    }
  }
}

// Out[e,:] = Ein[e,:]@W + A[src[e],:] + B[dst[e],:] + bias  (in-place safe)
// optional fused next-layer elr[e] = dot(Out[e,:], v)
template<int K, bool ELR>
__global__ __launch_bounds__(256,4) void k_edgegemm_t(const float* __restrict__ Ein,
    const float* __restrict__ W,
    const float* __restrict__ A, const float* __restrict__ B,
    const int* __restrict__ src, const int* __restrict__ dst,
    const float* __restrict__ bias, float* __restrict__ Out,
    const float* __restrict__ v, float* __restrict__ elr){
  __shared__ float Wl[K*HD];
  for (int idx=threadIdx.x; idx<K*HD/4; idx+=256)
    ((float4*)Wl)[idx] = ((const float4*)W)[idx];
  __syncthreads();
  const int r  = threadIdx.x >> 3;
  const int c0 = (threadIdx.x & 7)*12;
  const int e0 = blockIdx.x*128 + r;        // NE % 128 == 0, no bounds checks
  float acc[4][12];
  #pragma unroll
  for (int q=0;q<4;q++)
    #pragma unroll
    for (int j=0;j<12;j++) acc[q][j]=0.f;
  const float* e_base = Ein + (size_t)e0*K;
  for (int k=0;k<K;k+=4){
    float4 xv[4];
    #pragma unroll
    for (int q=0;q<4;q++)
      xv[q] = *(const float4*)(e_base + (size_t)(32*q)*K + k);
    #pragma unroll
    for (int kk=0;kk<4;kk++){
      float wv[12];
      const float* wr = Wl + (k+kk)*HD + c0;
      #pragma unroll
      for (int j=0;j<12;j++) wv[j] = wr[j];
      #pragma unroll
      for (int q=0;q<4;q++){
        float xs = ((const float*)&xv[q])[kk];
        #pragma unroll
        for (int j=0;j<12;j++) acc[q][j] += xs*wv[j];
      }
    }
  }
  __syncthreads();    // in-place safety: all reads of this block's tile done
  float bj[12], vv[12];
  #pragma unroll
  for (int j=0;j<12;j++) bj[j] = bias[c0+j];
  if constexpr (ELR){
    #pragma unroll
    for (int j=0;j<12;j++) vv[j] = v[c0+j];
  }
  #pragma unroll
  for (int q=0;q<4;q++){
    int e = e0 + 32*q;
    int s = src[e], d = dst[e];
    const float* Ar = A + (size_t)s*HD + c0;
    const float* Br = B + (size_t)d*HD + c0;
    float* orow = Out + (size_t)e*HD + c0;
    float pd = 0.f;
    #pragma unroll
    for (int j=0;j<12;j++){
      float o = acc[q][j] + Ar[j] + Br[j] + bj[j];
      orow[j] = o;
      if constexpr (ELR) pd += o*vv[j];
    }
    if constexpr (ELR){
      pd += __shfl_xor(pd,1,64);
      pd += __shfl_xor(pd,2,64);
      pd += __shfl_xor(pd,4,64);
      if ((threadIdx.x&7)==0) elr[e] = pd;
    }
  }
}

// ---- GAT softmax + aggregation (one wave per node; slp fused) -----------
__global__ __launch_bounds__(256) void k_gat(const int* __restrict__ rowptr,
    const int* __restrict__ src_s, const int* __restrict__ perm,
    const float* __restrict__ hs, const float* __restrict__ hd,
    const float* __restrict__ elr,
    const float* __restrict__ h, const float* __restrict__ bias,
    float* __restrict__ Out){
  int lane = threadIdx.x & 63;
  int n = blockIdx.x*4 + (threadIdx.x >> 6);
  if (n >= NN) return;
  int beg = rowptr[n], end = rowptr[n+1];
  float hdn = hd[n];
  // pass 1: neighbor max + elr segment-sum (for self-loop mean) in one sweep
  float mxn = -INFINITY;
  float se  = 0.f;
  for (int i = beg + lane; i < end; i += 64){
    float el = elr[perm[i]];
    se += el;
    mxn = fmaxf(mxn, lrelu(hs[src_s[i]] + hdn + el));
  }
  #pragma unroll
  for (int o=32;o>0;o>>=1){
    mxn = fmaxf(mxn, __shfl_xor(mxn, o, 64));
    se += __shfl_xor(se, o, 64);
  }
  float slp = se / fmaxf((float)(end-beg), 1.f);
  float selfL = lrelu(hs[n] + hdn + slp);
  float mx = fmaxf(mxn, selfL);
  // pass 2: weighted aggregation
  float acc0 = 0.f, acc1 = 0.f, denom = 0.f;
  for (int i = beg; i < end; ++i){
    int s = src_s[i];
    float p = __expf(lrelu(hs[s] + hdn + elr[perm[i]]) - mx);
    denom += p;
    acc0 += p * h[(size_t)s*HD + lane];
    if (lane < 32) acc1 += p * h[(size_t)s*HD + 64 + lane];
  }
  float ps = __expf(selfL - mx);
  denom += ps;
  acc0 += ps * h[(size_t)n*HD + lane];
  if (lane < 32) acc1 += ps * h[(size_t)n*HD + 64 + lane];
  float inv = 1.f/denom;
  Out[(size_t)n*HD + lane] = acc0*inv + bias[lane];
  if (lane < 32) Out[(size_t)n*HD + 64 + lane] = acc1*inv + bias[64+lane];
}

// ---- driver -------------------------------------------------------------
extern "C" void kernel_launch(void* const* d_in, const int* in_sizes, int n_in,
                              void* d_out, int out_size, void* d_ws, size_t ws_size,
                              hipStream_t stream){
  const float* x   = (const float*)d_in[0];
  const int*   ei  = (const int*)d_in[1];
  const float* ea  = (const float*)d_in[2];
  const float* w0  = (const float*)d_in[3];
  const float* we0 = (const float*)d_in[4];
  const float* as0 = (const float*)d_in[5];
  const float* ad0 = (const float*)d_in[6];
  const float* ae0 = (const float*)d_in[7];
  const float* b0  = (const float*)d_in[8];
  const float* ew0 = (const float*)d_in[9];
  const float* eb0 = (const float*)d_in[10];
  const float* w1  = (const float*)d_in[11];
  const float* we1 = (const float*)d_in[12];
  const float* as1 = (const float*)d_in[13];
  const float* ad1 = (const float*)d_in[14];
  const float* ae1 = (const float*)d_in[15];
  const float* b1  = (const float*)d_in[16];
  const float* ew1 = (const float*)d_in[17];
  const float* eb1 = (const float*)d_in[18];

  const int* srcp = ei;
  const int* dstp = ei + NE;

  char* ws = (char*)d_ws;
  size_t off = 0;
  auto carve = [&](size_t bytes)->char*{
    char* p = ws + off; off += (bytes + 255) & ~(size_t)255; return p;
  };
  int*   rowptr = (int*)carve(4ull*(NN+1));
  int*   fillc  = (int*)carve(4ull*NN);
  int*   perm   = (int*)carve(4ull*NE);
  int*   src_s  = (int*)carve(4ull*NE);
  float* hbuf   = (float*)carve(4ull*NN*HD);
  float* x0     = (float*)carve(4ull*NN*HD);
  float* Ab     = (float*)carve(4ull*NN*HD);
  float* Bb     = (float*)carve(4ull*NN*HD);
  float* hsb    = (float*)carve(4ull*NN);
  float* hdb    = (float*)carve(4ull*NN);
  float* elr    = (float*)carve(4ull*NE);
  float* vsm0   = (float*)carve(4ull*128);
  float* vsm1   = (float*)carve(4ull*128);
  (void)ws_size; (void)in_sizes; (void)n_in; (void)out_size;

  float* xout  = (float*)d_out;                    // [NN,HD]
  float* eaout = (float*)d_out + (size_t)NN*HD;    // [NE,HD]

  const int EB  = (NE + 255)/256;
  const int GE  = NE/128;            // 6250, exact
  const int GN  = (NN + 127)/128;    // 391

  // CSR (by dst), built fresh every launch
  hipMemsetAsync(fillc, 0, 4ull*NN, stream);
  k_count<<<EB, 256, 0, stream>>>(dstp, fillc);
  k_scan<<<1, 1024, 0, stream>>>(fillc, rowptr);
  hipMemsetAsync(fillc, 0, 4ull*NN, stream);
  k_fill<<<EB, 256, 0, stream>>>(srcp, dstp, rowptr, fillc, perm, src_s);

  // attention edge-vectors for both layers
  k_vec<<<1, 128, 0, stream>>>(we0, ae0, vsm0, DEDGE);
  k_vec<<<1, 128, 0, stream>>>(we1, ae1, vsm1, HD);

  // ---- layer 0 ----
  k_elr<<<EB, 256, 0, stream>>>(ea, vsm0, elr, DEDGE);
  k_nodegemm_t<DNODE,true><<<GN, 256, 0, stream>>>(x, w0, hbuf, NN, as0, ad0, hsb, hdb);
  k_gat<<<(NN+3)/4, 256, 0, stream>>>(rowptr, src_s, perm, hsb, hdb, elr, hbuf, b0, x0);

  // edge update 0: eaout = ea@ew0[192:] + (x0@ew0[0:96])[src] + (x0@ew0[96:192])[dst] + eb0
  // fused: elr(layer1)[e] = dot(eaout[e,:], vsm1)
  k_nodegemm_t<HD,false><<<GN, 256, 0, stream>>>(x0, ew0,         Ab, NN, nullptr, nullptr, nullptr, nullptr);
  k_nodegemm_t<HD,false><<<GN, 256, 0, stream>>>(x0, ew0 + 96*HD, Bb, NN, nullptr, nullptr, nullptr, nullptr);
  k_edgegemm_t<DEDGE,true><<<GE, 256, 0, stream>>>(ea, ew0 + 192*HD, Ab, Bb, srcp, dstp,
                                                   eb0, eaout, vsm1, elr);

  // ---- layer 1 ----
  k_nodegemm_t<HD,true><<<GN, 256, 0, stream>>>(x0, w1, hbuf, NN, as1, ad1, hsb, hdb);
  k_gat<<<(NN+3)/4, 256, 0, stream>>>(rowptr, src_s, perm, hsb, hdb, elr, hbuf, b1, xout);

  // edge update 1 (in-place on eaout)
  k_nodegemm_t<HD,false><<<GN, 256, 0, stream>>>(xout, ew1,         Ab, NN, nullptr, nullptr, nullptr, nullptr);
  k_nodegemm_t<HD,false><<<GN, 256, 0, stream>>>(xout, ew1 + 96*HD, Bb, NN, nullptr, nullptr, nullptr, nullptr);
  k_edgegemm_t<HD,false><<<GE, 256, 0, stream>>>(eaout, ew1 + 192*HD, Ab, Bb, srcp, dstp,
                                                 eb1, eaout, nullptr, nullptr);
}